// Round 19
// baseline (32.735 us; speedup 1.0000x reference)
//
#include <hip/hip_runtime.h>

#define CUTN 128
#define CUT_SIZE 224
#define IMG_H 1024
#define IMG_W 1024
#define PAD 256          // IMG_H / 4
#define SIDE 1536        // IMG_H + 2*PAD
#define PX_PER_CUT (CUT_SIZE * CUT_SIZE)       // 50176
#define HALF_W 112                             // x-pairs per row
#define BLOCKS_PER_CUT 98                      // 224*112/256
#define PLANE_PX (IMG_H * IMG_W)

typedef float f32x2 __attribute__((ext_vector_type(2)));

// f32 (3,H,W) -> u8 planar (3,H,W). Thread i handles 4 px of the flat array.
__global__ __launch_bounds__(256) void convert_kernel(
    const float* __restrict__ img, unsigned char* __restrict__ dst)
{
    const int i = blockIdx.x * 256 + threadIdx.x;    // quad index
    if (i >= 3 * PLANE_PX / 4) return;
    const size_t p = 4 * (size_t)i;

    float4 v;
    __builtin_memcpy(&v, img + p, 16);
    const unsigned int b0 = (unsigned int)(v.x * 255.0f + 0.5f);
    const unsigned int b1 = (unsigned int)(v.y * 255.0f + 0.5f);
    const unsigned int b2 = (unsigned int)(v.z * 255.0f + 0.5f);
    const unsigned int b3 = (unsigned int)(v.w * 255.0f + 0.5f);
    const unsigned int o = b0 | (b1 << 8) | (b2 << 16) | (b3 << 24);
    __builtin_memcpy(dst + p, &o, 4);
}

// Round-18 structure (XCD-band remap, ballot dedupe, x-pair 2px/thread,
// folded weights, dwordx2 NT stores) with PLANAR U8 reads: per (px,row,ch)
// one ushort load covers both x-taps (adjacent bytes). 3 B/px, ~25% fewer
// line-touches than RGBA8.
template<bool HALFP>
__global__ __launch_bounds__(256) void make_cutouts_kernel(
    const float* __restrict__ img,              // (3,1024,1024) f32
    const unsigned char* __restrict__ img8,     // (3,1024,1024) u8 planar
    const int* __restrict__ sizes_y,
    const int* __restrict__ sizes_x,
    const int* __restrict__ offs_y,
    const int* __restrict__ offs_x,
    float* __restrict__ out)                    // (128,3,224,224)
{
    const int bid = blockIdx.x;
    const int k = bid & 7;               // XCD id under round-robin dispatch
    const int j = bid >> 3;              // 0..1567 local index within XCD

    int cut, blk;
    if (j < 1536) {
        cut = j / 12;                    // cut-major: 12 blocks per cut
        blk = k * 12 + (j - cut * 12);   // vertical chunk k of this cut
    } else {
        const int e = j - 1536;          // 0..31: leftover blocks
        cut = (k >> 1) + (e << 2);       // cuts m ≡ k>>1 (mod 4)
        blk = 96 + (k & 1);
    }

    const int lane = (int)(threadIdx.x & 63);

    const int sy = sizes_y[cut], sx = sizes_x[cut];
    const int oy = offs_y[cut],  ox = offs_x[cut];

    // ---- ballot dedupe: lane l checks cuts l and l+64 ----
    const bool eq_lo = (sizes_y[lane]      == sy) & (sizes_x[lane]      == sx) &
                       (offs_y[lane]       == oy) & (offs_x[lane]       == ox);
    const bool eq_hi = (sizes_y[lane + 64] == sy) & (sizes_x[lane + 64] == sx) &
                       (offs_y[lane + 64]  == oy) & (offs_x[lane + 64]  == ox);
    const unsigned long long mlo = __ballot(eq_lo);
    const unsigned long long mhi = __ballot(eq_hi);
    const int canon = mlo ? (__ffsll(mlo) - 1) : (__ffsll(mhi) + 63);
    if (canon != cut) return;            // an earlier identical cutout owns this

    const float syf = (float)sy, sxf = (float)sx;
    const float oyf = (float)oy, oxf = (float)ox;

    const int T  = blk * 256 + (int)threadIdx.x;     // 0..25087
    const int y  = T / HALF_W;                       // 0..223
    const int xh = T - y * HALF_W;                   // 0..111
    const int xb = xh * 2;                           // first of 2 px

    // ---- y-side (shared by both pixels) ----
    const float gy = ((float)y + 0.5f) / (float)CUT_SIZE;
    const float ysf = fminf(fmaxf(oyf + gy * syf - 0.5f, 0.0f), (float)(SIDE - 1));
    const int   y0 = (int)floorf(ysf);
    const float wy = ysf - (float)y0;
    const int  yy0 = y0 - PAD;
    const int  yy1 = min(y0 + 1, SIDE - 1) - PAD;
    const float wyl0 = ((unsigned)yy0 < (unsigned)IMG_H) ? (1.0f - wy) : 0.0f;
    const float wyl1 = ((unsigned)yy1 < (unsigned)IMG_H) ? wy          : 0.0f;
    const int   r0 = min(max(yy0, 0), IMG_H - 1);
    const int   r1 = min(max(yy1, 0), IMG_H - 1);

    const float qscale = HALFP ? (1.0f / 255.0f) : 1.0f;

    float vout[2][3];

    #pragma unroll
    for (int i = 0; i < 2; ++i) {
        const int x = xb + i;
        const float gx = ((float)x + 0.5f) / (float)CUT_SIZE;
        const float xs = fminf(fmaxf(oxf + gx * sxf - 0.5f, 0.0f), (float)(SIDE - 1));
        const int   x0 = (int)floorf(xs);
        const float wx = xs - (float)x0;
        const int  xx0 = x0 - PAD;
        const int  xx1 = min(x0 + 1, SIDE - 1) - PAD;
        const bool vx0 = (unsigned)xx0 < (unsigned)IMG_W;
        const bool vx1 = (unsigned)xx1 < (unsigned)IMG_W;
        const int   ax = min(max(xx0, 0), IMG_W - 2);
        const bool  s0 = (xx0 != ax);
        const bool  s1 = (xx1 == ax);
        const float cx_x = (((vx0 && !s0) ? (1.0f - wx) : 0.0f)
                          + ((vx1 &&  s1) ? wx          : 0.0f)) * qscale;
        const float cx_y = (((vx0 &&  s0) ? (1.0f - wx) : 0.0f)
                          + ((vx1 && !s1) ? wx          : 0.0f)) * qscale;
        const float cax = wyl0 * cx_x;
        const float cay = wyl0 * cx_y;
        const float cbx = wyl1 * cx_x;
        const float cby = wyl1 * cx_y;

        if constexpr (HALFP) {
            const int o0 = r0 * IMG_W + ax;
            const int o1 = r1 * IMG_W + ax;
            #pragma unroll
            for (int c = 0; c < 3; ++c) {
                const unsigned char* plane = img8 + c * PLANE_PX;
                unsigned short ua, ub;
                __builtin_memcpy(&ua, plane + o0, 2);   // bytes {ax, ax+1}
                __builtin_memcpy(&ub, plane + o1, 2);
                const float a0 = (float)(ua & 0xffu);
                const float a1 = (float)(ua >> 8);
                const float b0 = (float)(ub & 0xffu);
                const float b1 = (float)(ub >> 8);
                vout[i][c] = a0 * cax + a1 * cay + b0 * cbx + b1 * cby;
            }
        } else {
            const int o0 = r0 * IMG_W + ax;
            const int o1 = r1 * IMG_W + ax;
            #pragma unroll
            for (int c = 0; c < 3; ++c) {
                const float* plane = img + c * PLANE_PX;
                float2 a, b;
                __builtin_memcpy(&a, plane + o0, 8);
                __builtin_memcpy(&b, plane + o1, 8);
                vout[i][c] = a.x * cax + a.y * cay + b.x * cbx + b.y * cby;
            }
        }
    }

    // ---- write own cutout and all duplicates: 3 dwordx2 NT stores each ----
    const int pix = y * CUT_SIZE + xb;               // even => 8B-aligned
    unsigned long long lo = mlo, hi = mhi;
    while (lo) {
        const int d = __ffsll(lo) - 1; lo &= lo - 1;
        const int obase = (d * 3) * PX_PER_CUT + pix;
        #pragma unroll
        for (int c = 0; c < 3; ++c) {
            f32x2 v = { vout[0][c], vout[1][c] };
            __builtin_nontemporal_store(v, (f32x2*)&out[obase + c * PX_PER_CUT]);
        }
    }
    while (hi) {
        const int d = __ffsll(hi) + 63; hi &= hi - 1;
        const int obase = (d * 3) * PX_PER_CUT + pix;
        #pragma unroll
        for (int c = 0; c < 3; ++c) {
            f32x2 v = { vout[0][c], vout[1][c] };
            __builtin_nontemporal_store(v, (f32x2*)&out[obase + c * PX_PER_CUT]);
        }
    }
}

extern "C" void kernel_launch(void* const* d_in, const int* in_sizes, int n_in,
                              void* d_out, int out_size, void* d_ws, size_t ws_size,
                              hipStream_t stream) {
    const float* img     = (const float*)d_in[0];
    const int*   sizes_y = (const int*)d_in[1];
    const int*   sizes_x = (const int*)d_in[2];
    const int*   offs_y  = (const int*)d_in[3];
    const int*   offs_x  = (const int*)d_in[4];
    float* out = (float*)d_out;

    const int grid = CUTN * BLOCKS_PER_CUT;   // 12544 blocks of 256
    const size_t need = (size_t)3 * PLANE_PX;  // 3 MB u8 planar

    if (ws_size >= need) {
        unsigned char* img8 = (unsigned char*)d_ws;
        const int cgrid = (3 * PLANE_PX / 4 + 255) / 256;    // 3072
        convert_kernel<<<cgrid, 256, 0, stream>>>(img, img8);
        make_cutouts_kernel<true><<<grid, 256, 0, stream>>>(
            img, img8, sizes_y, sizes_x, offs_y, offs_x, out);
    } else {
        make_cutouts_kernel<false><<<grid, 256, 0, stream>>>(
            img, nullptr, sizes_y, sizes_x, offs_y, offs_x, out);
    }
}

// Round 20
// 30.023 us; speedup vs baseline: 1.0903x; 1.0903x over previous
//
#include <hip/hip_runtime.h>

#define CUTN 128
#define CUT_SIZE 224
#define IMG_H 1024
#define IMG_W 1024
#define PAD 256          // IMG_H / 4
#define SIDE 1536        // IMG_H + 2*PAD
#define PX_PER_CUT (CUT_SIZE * CUT_SIZE)       // 50176
#define HALF_W 112                             // x-pairs per row
#define BLOCKS_PER_CUT 98                      // 224*112/256
#define PLANE_PX (IMG_H * IMG_W)

typedef float f32x2 __attribute__((ext_vector_type(2)));

// f32 planar (3,H,W) -> RGBA8 interleaved (H,W,4B). Thread i handles 2 px.
__global__ __launch_bounds__(256) void convert_kernel(
    const float* __restrict__ img, unsigned int* __restrict__ dst)
{
    const int i = blockIdx.x * 256 + threadIdx.x;    // pair index
    if (i >= PLANE_PX / 2) return;
    const size_t p = 2 * (size_t)i;

    float2 r, g, b;
    __builtin_memcpy(&r, img + p, 8);
    __builtin_memcpy(&g, img + PLANE_PX + p, 8);
    __builtin_memcpy(&b, img + 2 * PLANE_PX + p, 8);

    const unsigned int r0 = (unsigned int)(r.x * 255.0f + 0.5f);
    const unsigned int g0 = (unsigned int)(g.x * 255.0f + 0.5f);
    const unsigned int b0 = (unsigned int)(b.x * 255.0f + 0.5f);
    const unsigned int r1 = (unsigned int)(r.y * 255.0f + 0.5f);
    const unsigned int g1 = (unsigned int)(g.y * 255.0f + 0.5f);
    const unsigned int b1 = (unsigned int)(b.y * 255.0f + 0.5f);

    uint2 o;
    o.x = r0 | (g0 << 8) | (b0 << 16);
    o.y = r1 | (g1 << 8) | (b1 << 16);
    __builtin_memcpy(dst + p, &o, 8);
}

// Best configuration (round 18): XCD-band remap, ballot dedupe, RGBA8
// interleaved reads (one 8B load per px/row-tap = both x-taps x 3 ch),
// x-pair 2px/thread, folded validity/clamp/dequant weights, dwordx2 NT
// stores. 30.5 us measured.
template<bool HALFP>
__global__ __launch_bounds__(256) void make_cutouts_kernel(
    const float* __restrict__ img,              // (3,1024,1024) f32
    const unsigned char* __restrict__ img8,     // (1024,1024,4) RGBA8
    const int* __restrict__ sizes_y,
    const int* __restrict__ sizes_x,
    const int* __restrict__ offs_y,
    const int* __restrict__ offs_x,
    float* __restrict__ out)                    // (128,3,224,224)
{
    const int bid = blockIdx.x;
    const int k = bid & 7;               // XCD id under round-robin dispatch
    const int j = bid >> 3;              // 0..1567 local index within XCD

    int cut, blk;
    if (j < 1536) {
        cut = j / 12;                    // cut-major: 12 blocks per cut
        blk = k * 12 + (j - cut * 12);   // vertical chunk k of this cut
    } else {
        const int e = j - 1536;          // 0..31: leftover blocks
        cut = (k >> 1) + (e << 2);       // cuts m ≡ k>>1 (mod 4)
        blk = 96 + (k & 1);
    }

    const int lane = (int)(threadIdx.x & 63);

    const int sy = sizes_y[cut], sx = sizes_x[cut];
    const int oy = offs_y[cut],  ox = offs_x[cut];

    // ---- ballot dedupe: lane l checks cuts l and l+64 ----
    const bool eq_lo = (sizes_y[lane]      == sy) & (sizes_x[lane]      == sx) &
                       (offs_y[lane]       == oy) & (offs_x[lane]       == ox);
    const bool eq_hi = (sizes_y[lane + 64] == sy) & (sizes_x[lane + 64] == sx) &
                       (offs_y[lane + 64]  == oy) & (offs_x[lane + 64]  == ox);
    const unsigned long long mlo = __ballot(eq_lo);
    const unsigned long long mhi = __ballot(eq_hi);
    const int canon = mlo ? (__ffsll(mlo) - 1) : (__ffsll(mhi) + 63);
    if (canon != cut) return;            // an earlier identical cutout owns this

    const float syf = (float)sy, sxf = (float)sx;
    const float oyf = (float)oy, oxf = (float)ox;

    const int T  = blk * 256 + (int)threadIdx.x;     // 0..25087
    const int y  = T / HALF_W;                       // 0..223
    const int xh = T - y * HALF_W;                   // 0..111
    const int xb = xh * 2;                           // first of 2 px

    // ---- y-side (shared by both pixels) ----
    const float gy = ((float)y + 0.5f) / (float)CUT_SIZE;
    const float ysf = fminf(fmaxf(oyf + gy * syf - 0.5f, 0.0f), (float)(SIDE - 1));
    const int   y0 = (int)floorf(ysf);
    const float wy = ysf - (float)y0;
    const int  yy0 = y0 - PAD;
    const int  yy1 = min(y0 + 1, SIDE - 1) - PAD;
    const float wyl0 = ((unsigned)yy0 < (unsigned)IMG_H) ? (1.0f - wy) : 0.0f;
    const float wyl1 = ((unsigned)yy1 < (unsigned)IMG_H) ? wy          : 0.0f;
    const int   r0 = min(max(yy0, 0), IMG_H - 1);
    const int   r1 = min(max(yy1, 0), IMG_H - 1);

    const float qscale = HALFP ? (1.0f / 255.0f) : 1.0f;

    float vout[2][3];

    #pragma unroll
    for (int i = 0; i < 2; ++i) {
        const int x = xb + i;
        const float gx = ((float)x + 0.5f) / (float)CUT_SIZE;
        const float xs = fminf(fmaxf(oxf + gx * sxf - 0.5f, 0.0f), (float)(SIDE - 1));
        const int   x0 = (int)floorf(xs);
        const float wx = xs - (float)x0;
        const int  xx0 = x0 - PAD;
        const int  xx1 = min(x0 + 1, SIDE - 1) - PAD;
        const bool vx0 = (unsigned)xx0 < (unsigned)IMG_W;
        const bool vx1 = (unsigned)xx1 < (unsigned)IMG_W;
        const int   ax = min(max(xx0, 0), IMG_W - 2);
        const bool  s0 = (xx0 != ax);
        const bool  s1 = (xx1 == ax);
        const float cx_x = (((vx0 && !s0) ? (1.0f - wx) : 0.0f)
                          + ((vx1 &&  s1) ? wx          : 0.0f)) * qscale;
        const float cx_y = (((vx0 &&  s0) ? (1.0f - wx) : 0.0f)
                          + ((vx1 && !s1) ? wx          : 0.0f)) * qscale;
        const float cax = wyl0 * cx_x;
        const float cay = wyl0 * cx_y;
        const float cbx = wyl1 * cx_x;
        const float cby = wyl1 * cx_y;

        if constexpr (HALFP) {
            uint2 A, B;
            __builtin_memcpy(&A, img8 + (size_t)(r0 * IMG_W + ax) * 4, 8);
            __builtin_memcpy(&B, img8 + (size_t)(r1 * IMG_W + ax) * 4, 8);
            #pragma unroll
            for (int c = 0; c < 3; ++c) {
                const float a0 = (float)((A.x >> (8 * c)) & 0xffu);
                const float a1 = (float)((A.y >> (8 * c)) & 0xffu);
                const float b0 = (float)((B.x >> (8 * c)) & 0xffu);
                const float b1 = (float)((B.y >> (8 * c)) & 0xffu);
                vout[i][c] = a0 * cax + a1 * cay + b0 * cbx + b1 * cby;
            }
        } else {
            const int o0 = r0 * IMG_W + ax;
            const int o1 = r1 * IMG_W + ax;
            #pragma unroll
            for (int c = 0; c < 3; ++c) {
                const float* plane = img + c * PLANE_PX;
                float2 a, b;
                __builtin_memcpy(&a, plane + o0, 8);
                __builtin_memcpy(&b, plane + o1, 8);
                vout[i][c] = a.x * cax + a.y * cay + b.x * cbx + b.y * cby;
            }
        }
    }

    // ---- write own cutout and all duplicates: 3 dwordx2 NT stores each ----
    const int pix = y * CUT_SIZE + xb;               // even => 8B-aligned
    unsigned long long lo = mlo, hi = mhi;
    while (lo) {
        const int d = __ffsll(lo) - 1; lo &= lo - 1;
        const int obase = (d * 3) * PX_PER_CUT + pix;
        #pragma unroll
        for (int c = 0; c < 3; ++c) {
            f32x2 v = { vout[0][c], vout[1][c] };
            __builtin_nontemporal_store(v, (f32x2*)&out[obase + c * PX_PER_CUT]);
        }
    }
    while (hi) {
        const int d = __ffsll(hi) + 63; hi &= hi - 1;
        const int obase = (d * 3) * PX_PER_CUT + pix;
        #pragma unroll
        for (int c = 0; c < 3; ++c) {
            f32x2 v = { vout[0][c], vout[1][c] };
            __builtin_nontemporal_store(v, (f32x2*)&out[obase + c * PX_PER_CUT]);
        }
    }
}

extern "C" void kernel_launch(void* const* d_in, const int* in_sizes, int n_in,
                              void* d_out, int out_size, void* d_ws, size_t ws_size,
                              hipStream_t stream) {
    const float* img     = (const float*)d_in[0];
    const int*   sizes_y = (const int*)d_in[1];
    const int*   sizes_x = (const int*)d_in[2];
    const int*   offs_y  = (const int*)d_in[3];
    const int*   offs_x  = (const int*)d_in[4];
    float* out = (float*)d_out;

    const int grid = CUTN * BLOCKS_PER_CUT;   // 12544 blocks of 256
    const size_t need = (size_t)PLANE_PX * 4;  // 4 MB RGBA8

    if (ws_size >= need) {
        unsigned int* img8 = (unsigned int*)d_ws;
        const int cgrid = (PLANE_PX / 2 + 255) / 256;    // 2048
        convert_kernel<<<cgrid, 256, 0, stream>>>(img, img8);
        make_cutouts_kernel<true><<<grid, 256, 0, stream>>>(
            img, (const unsigned char*)img8, sizes_y, sizes_x,
            offs_y, offs_x, out);
    } else {
        make_cutouts_kernel<false><<<grid, 256, 0, stream>>>(
            img, nullptr, sizes_y, sizes_x, offs_y, offs_x, out);
    }
}